// Round 1
// baseline (2111.776 us; speedup 1.0000x reference)
//
#include <hip/hip_runtime.h>
#include <hip/hip_bf16.h>

#define N     4096
#define NIT   50
#define EPS   1e-8f
#define CHUNKS 64            // row chunks for column partial sums (4096/64 = 64 rows each)

// ---------------------------------------------------------------------------
// Kernel 1: row softmax of logits -> S (stored in d_out), init r = c = 1
// ---------------------------------------------------------------------------
__global__ void softmax_rows(const float* __restrict__ x, float* __restrict__ S,
                             float* __restrict__ r, float* __restrict__ c) {
    const int row = blockIdx.x;
    const int tid = threadIdx.x;
    const float4* xr = (const float4*)(x + (size_t)row * N);
    float4* Sr = (float4*)(S + (size_t)row * N);

    float4 v[4];
    float mx = -3.0e38f;
#pragma unroll
    for (int t = 0; t < 4; ++t) {
        v[t] = xr[tid + 256 * t];
        mx = fmaxf(mx, fmaxf(fmaxf(v[t].x, v[t].y), fmaxf(v[t].z, v[t].w)));
    }

    __shared__ float sm[4];
    // wave (64-lane) max reduce, then cross-wave via LDS
#pragma unroll
    for (int off = 32; off; off >>= 1) mx = fmaxf(mx, __shfl_down(mx, off));
    const int wid = tid >> 6, lane = tid & 63;
    if (lane == 0) sm[wid] = mx;
    __syncthreads();
    mx = fmaxf(fmaxf(sm[0], sm[1]), fmaxf(sm[2], sm[3]));
    __syncthreads();   // protect sm reuse below

    float sum = 0.f;
#pragma unroll
    for (int t = 0; t < 4; ++t) {
        v[t].x = __expf(v[t].x - mx);
        v[t].y = __expf(v[t].y - mx);
        v[t].z = __expf(v[t].z - mx);
        v[t].w = __expf(v[t].w - mx);
        sum += (v[t].x + v[t].y) + (v[t].z + v[t].w);
    }
#pragma unroll
    for (int off = 32; off; off >>= 1) sum += __shfl_down(sum, off);
    if (lane == 0) sm[wid] = sum;
    __syncthreads();
    sum = (sm[0] + sm[1]) + (sm[2] + sm[3]);

    const float inv = 1.0f / sum;
#pragma unroll
    for (int t = 0; t < 4; ++t) {
        float4 o;
        o.x = v[t].x * inv; o.y = v[t].y * inv;
        o.z = v[t].z * inv; o.w = v[t].w * inv;
        Sr[tid + 256 * t] = o;
    }

    // init scale vectors (first 16 blocks cover 4096 elements)
    if (blockIdx.x < 16) {
        const int k = blockIdx.x * 256 + tid;
        r[k] = 1.0f;
        c[k] = 1.0f;
    }
}

// ---------------------------------------------------------------------------
// Kernel 2: u[row] = dot(S[row,:], c);  r[row] = r[row] / (r[row]*u + eps)
// ---------------------------------------------------------------------------
__global__ void row_norm(const float* __restrict__ S, const float* __restrict__ c,
                         float* __restrict__ r) {
    const int row = blockIdx.x;
    const int tid = threadIdx.x;
    const float4* Sr = (const float4*)(S + (size_t)row * N);
    const float4* c4 = (const float4*)c;

    float acc = 0.f;
#pragma unroll
    for (int t = 0; t < 4; ++t) {
        const int k = tid + 256 * t;
        float4 s = Sr[k], cc = c4[k];
        acc = fmaf(s.x, cc.x, acc);
        acc = fmaf(s.y, cc.y, acc);
        acc = fmaf(s.z, cc.z, acc);
        acc = fmaf(s.w, cc.w, acc);
    }
#pragma unroll
    for (int off = 32; off; off >>= 1) acc += __shfl_down(acc, off);
    __shared__ float sm[4];
    const int wid = tid >> 6, lane = tid & 63;
    if (lane == 0) sm[wid] = acc;
    __syncthreads();
    if (tid == 0) {
        const float u  = (sm[0] + sm[1]) + (sm[2] + sm[3]);
        const float rr = r[row];
        r[row] = rr / (fmaf(rr, u, EPS));
    }
}

// ---------------------------------------------------------------------------
// Kernel 3a: column partial sums, deterministic (no atomics).
// grid = 16 col-slabs x CHUNKS row-chunks; part[chunk][j] = sum_{i in chunk} r[i]*S[i][j]
// ---------------------------------------------------------------------------
__global__ void col_partial(const float* __restrict__ S, const float* __restrict__ r,
                            float* __restrict__ part) {
    const int j     = (blockIdx.x & 15) * 256 + threadIdx.x;   // column (coalesced)
    const int chunk = blockIdx.x >> 4;
    const int i0    = chunk * (N / CHUNKS);

    float acc = 0.f;
#pragma unroll 8
    for (int i = i0; i < i0 + (N / CHUNKS); ++i)
        acc = fmaf(r[i], S[(size_t)i * N + j], acc);   // r[i] is block-uniform -> scalar load

    part[(size_t)chunk * N + j] = acc;
}

// ---------------------------------------------------------------------------
// Kernel 3b: v[j] = sum_chunk part[chunk][j];  c[j] = c[j] / (c[j]*v + eps)
// ---------------------------------------------------------------------------
__global__ void col_finish(const float* __restrict__ part, float* __restrict__ c) {
    const int j = blockIdx.x * 256 + threadIdx.x;
    float v = 0.f;
#pragma unroll
    for (int k = 0; k < CHUNKS; ++k) v += part[(size_t)k * N + j];
    const float cc = c[j];
    c[j] = cc / (fmaf(cc, v, EPS));
}

// ---------------------------------------------------------------------------
// Kernel 4: out[i][j] = r[i] * S[i][j] * c[j]   (in place on d_out)
// ---------------------------------------------------------------------------
__global__ void finalize(float* __restrict__ S, const float* __restrict__ r,
                         const float* __restrict__ c) {
    const int row = blockIdx.x;
    const int tid = threadIdx.x;
    const float rr = r[row];
    float4* Sr = (float4*)(S + (size_t)row * N);
    const float4* c4 = (const float4*)c;
#pragma unroll
    for (int t = 0; t < 4; ++t) {
        const int k = tid + 256 * t;
        float4 s = Sr[k], cc = c4[k];
        s.x *= rr * cc.x;
        s.y *= rr * cc.y;
        s.z *= rr * cc.z;
        s.w *= rr * cc.w;
        Sr[k] = s;
    }
}

extern "C" void kernel_launch(void* const* d_in, const int* in_sizes, int n_in,
                              void* d_out, int out_size, void* d_ws, size_t ws_size,
                              hipStream_t stream) {
    const float* logits = (const float*)d_in[0];
    float* S = (float*)d_out;                 // softmax matrix lives in d_out
    float* ws = (float*)d_ws;
    float* r    = ws;                          // [N]
    float* c    = ws + N;                      // [N]
    float* part = ws + 2 * N;                  // [CHUNKS][N] = 1 MB

    softmax_rows<<<N, 256, 0, stream>>>(logits, S, r, c);

    for (int it = 0; it < NIT; ++it) {
        row_norm   <<<N,          256, 0, stream>>>(S, c, r);
        col_partial<<<16 * CHUNKS, 256, 0, stream>>>(S, r, part);
        col_finish <<<16,         256, 0, stream>>>(part, c);
    }

    finalize<<<N, 256, 0, stream>>>(S, r, c);
}

// Round 2
// 1621.722 us; speedup vs baseline: 1.3022x; 1.3022x over previous
//
#include <hip/hip_runtime.h>
#include <hip/hip_bf16.h>

#define N            4096
#define NIT          50
#define EPS          1e-8f
#define PASS_BLOCKS  512
#define ROWS_PER_BLOCK (N / PASS_BLOCKS)     // 8
#define ROWS_PER_WAVE  (ROWS_PER_BLOCK / 4)  // 2

// ---- bf16 helpers (OCP bf16 = high 16 bits of f32) -------------------------
__device__ __forceinline__ unsigned bf16_rne(float f) {
    unsigned u = __float_as_uint(f);
    return (u + 0x7FFFu + ((u >> 16) & 1u)) >> 16;
}
__device__ __forceinline__ float bf_lo(unsigned u) { return __uint_as_float(u << 16); }
__device__ __forceinline__ float bf_hi(unsigned u) { return __uint_as_float(u & 0xFFFF0000u); }

// ---------------------------------------------------------------------------
// Kernel 1: row softmax of logits -> Sb (bf16), store per-row max & 1/sum,
//           init r = c = 1.  (No f32 S is materialized.)
// ---------------------------------------------------------------------------
__global__ void softmax_rows(const float* __restrict__ x, unsigned* __restrict__ Sb_u32,
                             float* __restrict__ mxv, float* __restrict__ siv,
                             float* __restrict__ r, float* __restrict__ c) {
    const int row = blockIdx.x;
    const int tid = threadIdx.x;
    const float4* xr = (const float4*)(x + (size_t)row * N);

    float4 v[4];
    float mx = -3.0e38f;
#pragma unroll
    for (int t = 0; t < 4; ++t) {
        v[t] = xr[tid + 256 * t];
        mx = fmaxf(mx, fmaxf(fmaxf(v[t].x, v[t].y), fmaxf(v[t].z, v[t].w)));
    }

    __shared__ float sm[4];
#pragma unroll
    for (int off = 32; off; off >>= 1) mx = fmaxf(mx, __shfl_down(mx, off));
    const int wid = tid >> 6, lane = tid & 63;
    if (lane == 0) sm[wid] = mx;
    __syncthreads();
    mx = fmaxf(fmaxf(sm[0], sm[1]), fmaxf(sm[2], sm[3]));
    __syncthreads();

    float sum = 0.f;
#pragma unroll
    for (int t = 0; t < 4; ++t) {
        v[t].x = __expf(v[t].x - mx);
        v[t].y = __expf(v[t].y - mx);
        v[t].z = __expf(v[t].z - mx);
        v[t].w = __expf(v[t].w - mx);
        sum += (v[t].x + v[t].y) + (v[t].z + v[t].w);
    }
#pragma unroll
    for (int off = 32; off; off >>= 1) sum += __shfl_down(sum, off);
    if (lane == 0) sm[wid] = sum;
    __syncthreads();
    sum = (sm[0] + sm[1]) + (sm[2] + sm[3]);

    const float inv = 1.0f / sum;
    uint2* Sb2 = (uint2*)(Sb_u32) + (size_t)row * (N / 4);   // uint2 = 4 bf16
#pragma unroll
    for (int t = 0; t < 4; ++t) {
        const int f = tid + 256 * t;
        uint2 pk;
        pk.x = bf16_rne(v[t].x * inv) | (bf16_rne(v[t].y * inv) << 16);
        pk.y = bf16_rne(v[t].z * inv) | (bf16_rne(v[t].w * inv) << 16);
        Sb2[f] = pk;
    }
    if (tid == 0) { mxv[row] = mx; siv[row] = inv; }

    if (blockIdx.x < 16) {
        const int k = blockIdx.x * 256 + tid;
        r[k] = 1.0f;
        c[k] = 1.0f;
    }
}

// ---------------------------------------------------------------------------
// Kernel 2 (fused row+col step): per block = 8 rows (2 per wave).
//  - cache c in regs; load row (bf16) into regs; u = dot(row, c) via wave
//    butterfly; r_new = r/(r*u+eps); acc[col] += r_new * row  (no re-read).
//  - LDS-reduce 4 waves -> part[block][col].
// ---------------------------------------------------------------------------
__global__ __launch_bounds__(256, 2)
void sinkhorn_pass(const uint4* __restrict__ Sb, float* __restrict__ r,
                   const float* __restrict__ c, float* __restrict__ part) {
    __shared__ float lds[4 * N];   // 64 KB
    const int b = blockIdx.x, tid = threadIdx.x;
    const int w = tid >> 6, l = tid & 63;

    // cache c: lane covers cols (l+64k)*8 + e, k=0..7, e=0..7
    float cv[64];
    const float4* c4 = (const float4*)c;
#pragma unroll
    for (int k = 0; k < 8; ++k) {
        const int f4 = (l + 64 * k) * 2;
        float4 a = c4[f4], d = c4[f4 + 1];
        cv[k*8+0]=a.x; cv[k*8+1]=a.y; cv[k*8+2]=a.z; cv[k*8+3]=a.w;
        cv[k*8+4]=d.x; cv[k*8+5]=d.y; cv[k*8+6]=d.z; cv[k*8+7]=d.w;
    }
    float acc[64];
#pragma unroll
    for (int e = 0; e < 64; ++e) acc[e] = 0.f;

    const int i0 = b * ROWS_PER_BLOCK + w * ROWS_PER_WAVE;
#pragma unroll
    for (int rr_ = 0; rr_ < ROWS_PER_WAVE; ++rr_) {
        const int i = i0 + rr_;
        const uint4* row = Sb + (size_t)i * (N / 8);
        uint4 q[8];
#pragma unroll
        for (int k = 0; k < 8; ++k) q[k] = row[l + 64 * k];

        float dot = 0.f;
#pragma unroll
        for (int k = 0; k < 8; ++k) {
            dot = fmaf(bf_lo(q[k].x), cv[k*8+0], dot);
            dot = fmaf(bf_hi(q[k].x), cv[k*8+1], dot);
            dot = fmaf(bf_lo(q[k].y), cv[k*8+2], dot);
            dot = fmaf(bf_hi(q[k].y), cv[k*8+3], dot);
            dot = fmaf(bf_lo(q[k].z), cv[k*8+4], dot);
            dot = fmaf(bf_hi(q[k].z), cv[k*8+5], dot);
            dot = fmaf(bf_lo(q[k].w), cv[k*8+6], dot);
            dot = fmaf(bf_hi(q[k].w), cv[k*8+7], dot);
        }
#pragma unroll
        for (int off = 32; off; off >>= 1) dot += __shfl_xor(dot, off);

        const float ro = r[i];
        const float rn = ro / fmaf(ro, dot, EPS);
        if (l == 0) r[i] = rn;

#pragma unroll
        for (int k = 0; k < 8; ++k) {
            acc[k*8+0] = fmaf(rn, bf_lo(q[k].x), acc[k*8+0]);
            acc[k*8+1] = fmaf(rn, bf_hi(q[k].x), acc[k*8+1]);
            acc[k*8+2] = fmaf(rn, bf_lo(q[k].y), acc[k*8+2]);
            acc[k*8+3] = fmaf(rn, bf_hi(q[k].y), acc[k*8+3]);
            acc[k*8+4] = fmaf(rn, bf_lo(q[k].z), acc[k*8+4]);
            acc[k*8+5] = fmaf(rn, bf_hi(q[k].z), acc[k*8+5]);
            acc[k*8+6] = fmaf(rn, bf_lo(q[k].w), acc[k*8+6]);
            acc[k*8+7] = fmaf(rn, bf_hi(q[k].w), acc[k*8+7]);
        }
    }

    // wave partials -> LDS in a permuted, conflict-free layout:
    // lds4[w*1024 + (2k+h)*64 + l]  holds column-float4  2l + 128k + h
    float4* lw = (float4*)lds + w * 1024;
#pragma unroll
    for (int k = 0; k < 8; ++k) {
#pragma unroll
        for (int h = 0; h < 2; ++h) {
            float4 t4;
            t4.x = acc[k*8 + 4*h + 0];
            t4.y = acc[k*8 + 4*h + 1];
            t4.z = acc[k*8 + 4*h + 2];
            t4.w = acc[k*8 + 4*h + 3];
            lw[(2*k + h) * 64 + l] = t4;
        }
    }
    __syncthreads();

    const float4* lr = (const float4*)lds;
    float4* p4 = (float4*)(part + (size_t)b * N);
#pragma unroll
    for (int m = 0; m < 4; ++m) {
        const int p = tid + 256 * m;
        const int j = p >> 6, ll = p & 63;
        float4 s0 = lr[p], s1 = lr[1024 + p], s2 = lr[2048 + p], s3 = lr[3072 + p];
        float4 s;
        s.x = (s0.x + s1.x) + (s2.x + s3.x);
        s.y = (s0.y + s1.y) + (s2.y + s3.y);
        s.z = (s0.z + s1.z) + (s2.z + s3.z);
        s.w = (s0.w + s1.w) + (s2.w + s3.w);
        const int col4 = 2 * ll + 128 * (j >> 1) + (j & 1);
        p4[col4] = s;
    }
}

// ---------------------------------------------------------------------------
// Kernel 3: v[j] = sum_b part[b][j];  c[j] = c[j]/(c[j]*v+eps)
// ---------------------------------------------------------------------------
__global__ void col_update(const float* __restrict__ part, float* __restrict__ c) {
    const int j = blockIdx.x * 64 + threadIdx.x;
    float v = 0.f;
#pragma unroll 8
    for (int ch = 0; ch < PASS_BLOCKS; ++ch)
        v += part[(size_t)ch * N + j];
    const float cc = c[j];
    c[j] = cc / fmaf(cc, v, EPS);
}

// ---------------------------------------------------------------------------
// Kernel 4: out[i][j] = r[i] * (exp(x[i][j]-mx[i])*siv[i]) * c[j]
// ---------------------------------------------------------------------------
__global__ void finalize(const float* __restrict__ x, const float* __restrict__ r,
                         const float* __restrict__ c, const float* __restrict__ mxv,
                         const float* __restrict__ siv, float* __restrict__ out) {
    const int row = blockIdx.x;
    const int tid = threadIdx.x;
    const float mx = mxv[row];
    const float sr = r[row] * siv[row];
    const float4* xr = (const float4*)(x + (size_t)row * N);
    float4* o4 = (float4*)(out + (size_t)row * N);
    const float4* c4 = (const float4*)c;
#pragma unroll
    for (int t = 0; t < 4; ++t) {
        const int k = tid + 256 * t;
        float4 xv = xr[k], cc = c4[k];
        float4 o;
        o.x = sr * __expf(xv.x - mx) * cc.x;
        o.y = sr * __expf(xv.y - mx) * cc.y;
        o.z = sr * __expf(xv.z - mx) * cc.z;
        o.w = sr * __expf(xv.w - mx) * cc.w;
        o4[k] = o;
    }
}

extern "C" void kernel_launch(void* const* d_in, const int* in_sizes, int n_in,
                              void* d_out, int out_size, void* d_ws, size_t ws_size,
                              hipStream_t stream) {
    const float* logits = (const float*)d_in[0];
    float* out = (float*)d_out;
    float* ws = (float*)d_ws;

    float* r    = ws;                          // [N]
    float* c    = ws + N;                      // [N]
    float* mxv  = ws + 2 * N;                  // [N]
    float* siv  = ws + 3 * N;                  // [N]
    float* part = ws + 4 * N;                  // [PASS_BLOCKS][N] = 8 MB
    unsigned* Sb = (unsigned*)(part + (size_t)PASS_BLOCKS * N);  // bf16 [N][N] = 32 MB

    softmax_rows<<<N, 256, 0, stream>>>(logits, Sb, mxv, siv, r, c);

    for (int it = 0; it < NIT; ++it) {
        sinkhorn_pass<<<PASS_BLOCKS, 256, 0, stream>>>((const uint4*)Sb, r, c, part);
        col_update  <<<N / 64,      64, 0, stream>>>(part, c);
    }

    finalize<<<N, 256, 0, stream>>>(logits, r, c, mxv, siv, out);
}